// Round 11
// baseline (70.003 us; speedup 1.0000x reference)
//
#include <hip/hip_runtime.h>
#include <hip/hip_bf16.h>
#include <stdint.h>

typedef float  f32x4  __attribute__((ext_vector_type(4)));
typedef __bf16 bf16x4 __attribute__((ext_vector_type(4)));
typedef __bf16 bf16x8 __attribute__((ext_vector_type(8)));
typedef unsigned int u32x2 __attribute__((ext_vector_type(2)));
typedef unsigned int u32x4 __attribute__((ext_vector_type(4)));

#define AS1 __attribute__((address_space(1)))
#define AS3 __attribute__((address_space(3)))

__device__ __forceinline__ void async_load16(const void* g, void* lds) {
    __builtin_amdgcn_global_load_lds((const AS1 unsigned int*)g,
                                     (AS3 unsigned int*)lds, 16, 0, 0);
}

// ---------------------------------------------------------------------------
// K1: qw[hs][k] = scale * sum_d q[h,s,d] * Wk[k, h*64+d]   (bf16, [hs][768])
// Written with element-index XOR swizzle (k ^ ((row&7)<<3)) so logits' LDS
// image (linear copy) gives bank-balanced bf16x8 reads.
// ---------------------------------------------------------------------------
__global__ __launch_bounds__(256) void qw_kernel(const float* __restrict__ q_emb,
                                                 const float* __restrict__ wk,
                                                 __bf16* __restrict__ qwT) {
    __shared__ float qlds[256];
    __shared__ float part[4096];  // [k 64][s 4][dseg 16]
    const int t = threadIdx.x;
    const int kc = blockIdx.x;   // 0..11
    const int h  = blockIdx.y;   // 0..15
    const int k0 = kc * 64;
    qlds[t] = q_emb[h * 256 + t] * 0.125f;   // scale = D^-0.5 = 1/8
    __syncthreads();
    const int dseg = t & 15;
    const int krow = t >> 4;   // 0..15
#pragma unroll
    for (int i = 0; i < 4; ++i) {
        const int k = i * 16 + krow;
        f32x4 wv = *(const f32x4*)&wk[(size_t)(k0 + k) * 1024 + h * 64 + dseg * 4];
#pragma unroll
        for (int s = 0; s < 4; ++s) {
            float p = qlds[s * 64 + dseg * 4 + 0] * wv[0]
                    + qlds[s * 64 + dseg * 4 + 1] * wv[1]
                    + qlds[s * 64 + dseg * 4 + 2] * wv[2]
                    + qlds[s * 64 + dseg * 4 + 3] * wv[3];
            part[k * 64 + s * 16 + dseg] = p;
        }
    }
    __syncthreads();
    const int k = t >> 2, s = t & 3;
    const float* pp = &part[k * 64 + s * 16];
    float sum = 0.f;
#pragma unroll
    for (int j = 0; j < 16; ++j) sum += pp[j];
    const int row = h * 4 + s;
    qwT[row * 768 + ((k0 + k) ^ ((row & 7) << 3))] = (__bf16)sum;
}

// ---------------------------------------------------------------------------
// K2: logits (bf16 out) + per-chunk softmax partials from ROUNDED values.
// BARRIER-FREE main loop: full qwT (96KB, swizzled) resident in LDS after one
// prologue barrier; A-fragments stream global->reg (depth-2 reg dbuf); no
// per-step barriers, waves free-run. BM=128 -> grid 256, 512 thr (8 waves).
// ---------------------------------------------------------------------------
__global__ __launch_bounds__(512) void logits_kernel(const float* __restrict__ x,
                                                     const __bf16* __restrict__ qwT,
                                                     const int* __restrict__ eos_idx,
                                                     __bf16* __restrict__ Lg,
                                                     float* __restrict__ partials) {
    __shared__ char smem[98304];   // [col 64][k 768] bf16 (src-swizzled image)
    const int t = threadIdx.x, l = t & 63, w = t >> 6;
    const int m0 = blockIdx.x * 128;
    const int bb = m0 >> 10, n0 = m0 & 1023;
    const int chunk = blockIdx.x & 7;
    const int wrA = (w >> 1) * 32;  // m(=n of attn) frag base
    const int wcB = (w & 1) * 32;   // hs base

    // ---- stage full qwT into LDS (linear 96KB copy, coalesced)
#pragma unroll
    for (int c = 0; c < 12; ++c)
        async_load16((const char*)qwT + c * 8192 + t * 16, smem + c * 8192 + t * 16);

    const int arow0 = m0 + wrA + (l & 15);
    const int kslot = (l >> 4) * 8;

    f32x4 acc[2][2];
#pragma unroll
    for (int i = 0; i < 2; ++i)
#pragma unroll
        for (int j = 0; j < 2; ++j) acc[i][j] = (f32x4)0.f;

    f32x4 aLo[4], aHi[4], bLo[4], bHi[4];   // frag idx = i*2+kh

    auto LOADA = [&](f32x4* lo, f32x4* hi, int kt) {
#pragma unroll
        for (int i = 0; i < 2; ++i)
#pragma unroll
            for (int kh = 0; kh < 2; ++kh) {
                const float* p = &x[(size_t)(arow0 + i * 16) * 768 + kt + kh * 32 + kslot];
                lo[i * 2 + kh] = *(const f32x4*)p;
                hi[i * 2 + kh] = *(const f32x4*)(p + 4);
            }
    };
    auto COMP = [&](const f32x4* lo, const f32x4* hi, int step) {
#pragma unroll
        for (int kh = 0; kh < 2; ++kh) {
            const int kk2 = (step * 64 + kh * 32 + kslot) * 2;
            bf16x8 bfr[2];
#pragma unroll
            for (int j = 0; j < 2; ++j) {
                const int col = wcB + j * 16 + (l & 15);
                bfr[j] = *(const bf16x8*)(smem + ((col * 1536 + kk2) ^ ((col & 7) << 4)));
            }
#pragma unroll
            for (int i = 0; i < 2; ++i) {
                f32x4 L = lo[i * 2 + kh], H = hi[i * 2 + kh];
                bf16x8 af = {(__bf16)L[0], (__bf16)L[1], (__bf16)L[2], (__bf16)L[3],
                             (__bf16)H[0], (__bf16)H[1], (__bf16)H[2], (__bf16)H[3]};
#pragma unroll
                for (int j = 0; j < 2; ++j)
                    acc[i][j] = __builtin_amdgcn_mfma_f32_16x16x32_bf16(
                        af, bfr[j], acc[i][j], 0, 0, 0);
            }
        }
    };

    LOADA(aLo, aHi, 0);
    asm volatile("s_waitcnt vmcnt(0)" ::: "memory");   // qwT image complete
    __syncthreads();

    // ---- barrier-free K loop (12 steps, manual depth-2 reg double-buffer)
#pragma unroll
    for (int it = 0; it < 6; ++it) {
        LOADA(bLo, bHi, (2 * it + 1) * 64);
        COMP(aLo, aHi, 2 * it);
        if (it < 5) LOADA(aLo, aHi, (2 * it + 2) * 64);
        COMP(bLo, bHi, 2 * it + 1);
    }
    __syncthreads();   // all waves done reading qwT image before reuse

    // ---- epilogue: frag -> LDS [hs 64][n 128] f32 -> mask, bf16-round,
    //      stats FROM ROUNDED values, bf16 store
#pragma unroll
    for (int i = 0; i < 2; ++i)
#pragma unroll
        for (int j = 0; j < 2; ++j) {
            const int hs = wcB + j * 16 + (l & 15);
            const int nb = wrA + i * 16 + (l >> 4) * 4;
            *(f32x4*)(smem + ((hs * 512 + nb * 4) ^ ((hs & 7) << 4))) = acc[i][j];
        }
    __syncthreads();
    const int eosb = eos_idx[bb];
    const int hs = t >> 3, seg7 = t & 7;
    const int fH = (hs & 7) << 4;
    float mx = -INFINITY;
    bf16x4 pk4[4];
#pragma unroll
    for (int i = 0; i < 4; ++i) {
        const int seg = seg7 + i * 8;
        f32x4 v = *(const f32x4*)(smem + ((hs * 512 + seg * 16) ^ fH));
        bf16x4 pk;
#pragma unroll
        for (int j = 0; j < 4; ++j) {
            const float f = (n0 + seg * 4 + j > eosb) ? -INFINITY : v[j];
            pk[j] = (__bf16)f;
            mx = fmaxf(mx, (float)pk[j]);
        }
        pk4[i] = pk;
        *(bf16x4*)&Lg[(size_t)bb * 65536 + hs * 1024 + n0 + seg * 4] = pk;
    }
#pragma unroll
    for (int off = 1; off < 8; off <<= 1) mx = fmaxf(mx, __shfl_xor(mx, off));
    float sl = 0.f;
    if (mx > -INFINITY) {
#pragma unroll
        for (int i = 0; i < 4; ++i)
#pragma unroll
            for (int j = 0; j < 4; ++j) sl += __expf((float)pk4[i][j] - mx);
    }
#pragma unroll
    for (int off = 1; off < 8; off <<= 1) sl += __shfl_xor(sl, off);
    if (seg7 == 0) {
        float2 st = {mx, sl};
        *(float2*)&partials[(size_t)(((bb * 8 + chunk) * 64) + hs) * 2] = st;
    }
}

// ---------------------------------------------------------------------------
// K3: y[b][hs][k] = sum_n softmax(Lg)[b,hs,n] * x[b,n,k]
// grid 384 = 32 b x 12 kc (XCD-swizzled), 256 thr, 16 n-steps, full n.
// ---------------------------------------------------------------------------
__global__ __launch_bounds__(256, 3) void pv_kernel(const float* __restrict__ x,
                                                    const __bf16* __restrict__ Lg,
                                                    const float* __restrict__ partials,
                                                    float* __restrict__ y) {
    __shared__ char smem[32768];
    char* Pl = smem;           // 2 x 8 KB  [hs 64][n 64] bf16, XOR ((row&7)<<4)
    char* Xl = smem + 16384;   // 2 x 8 KB  [k 64][n 64] bf16, XOR fK
    const int t = threadIdx.x, l = t & 63, w = t >> 6;
    const int vid = (blockIdx.x & 7) * 48 + (blockIdx.x >> 3);  // bijective XCD swizzle
    const int b = vid / 12, kc = vid % 12;
    const int k0 = kc * 64;
    const int wrA = (w >> 1) * 32, wcB = (w & 1) * 32;
    const __bf16* Lgb = Lg + (size_t)b * 65536;
    const float* xb = x + (size_t)b * 786432 + k0 + l;   // this thread's k-column
    const int fK = ((l & 7) << 4) | (((l >> 3) & 1) << 3);

    // ---- combine softmax partials (8 chunks) for this thread's two rows
    const int r0 = t >> 3, r1 = 32 + (t >> 3);
    float m0r, i0r, m1r, i1r;
    {
        const float* pb = partials + (size_t)b * 1024;  // [chunk 8][hs 64] float2
        float m = -INFINITY, m2 = -INFINITY;
#pragma unroll
        for (int c = 0; c < 8; ++c) {
            m  = fmaxf(m,  pb[(c * 64 + r0) * 2]);
            m2 = fmaxf(m2, pb[(c * 64 + r1) * 2]);
        }
        float s = 0.f, s2 = 0.f;
#pragma unroll
        for (int c = 0; c < 8; ++c) {
            float2 p0 = *(const float2*)&pb[(c * 64 + r0) * 2];
            float2 p1 = *(const float2*)&pb[(c * 64 + r1) * 2];
            s  += p0.y * __expf(p0.x - m);
            s2 += p1.y * __expf(p1.x - m2);
        }
        m0r = m; i0r = 1.0f / s;
        m1r = m2; i1r = 1.0f / s2;
    }
    const int n0s0 = (((t & 7) ^ (r0 & 7)) * 8);
    const int n0s1 = (((t & 7) ^ (r1 & 7)) * 8);

    f32x4 acc[2][2];
#pragma unroll
    for (int i = 0; i < 2; ++i)
#pragma unroll
        for (int j = 0; j < 2; ++j) acc[i][j] = (f32x4)0.f;

    auto STAGE = [&](int bufb, int T) {
        bf16x8 g0 = *(const bf16x8*)&Lgb[(size_t)r0 * 1024 + T * 64 + n0s0];
        bf16x8 g1 = *(const bf16x8*)&Lgb[(size_t)r1 * 1024 + T * 64 + n0s1];
        float xv[16];
#pragma unroll
        for (int i_ = 0; i_ < 4; ++i_)
#pragma unroll
            for (int j_ = 0; j_ < 4; ++j_)
                xv[i_ * 4 + j_] = xb[(size_t)(T * 64 + i_ * 16 + w * 4 + j_) * 768];
        bf16x8 pk;
#pragma unroll
        for (int j_ = 0; j_ < 8; ++j_)
            pk[j_] = (__bf16)(__expf((float)g0[j_] - m0r) * i0r);
        *(bf16x8*)(Pl + bufb * 8192 + t * 16) = pk;
#pragma unroll
        for (int j_ = 0; j_ < 8; ++j_)
            pk[j_] = (__bf16)(__expf((float)g1[j_] - m1r) * i1r);
        *(bf16x8*)(Pl + bufb * 8192 + 4096 + t * 16) = pk;
#pragma unroll
        for (int i_ = 0; i_ < 4; ++i_) {
            bf16x4 vv = {(__bf16)xv[i_ * 4 + 0], (__bf16)xv[i_ * 4 + 1],
                         (__bf16)xv[i_ * 4 + 2], (__bf16)xv[i_ * 4 + 3]};
            *(bf16x4*)(Xl + bufb * 8192 + ((l * 128 + (i_ * 16 + w * 4) * 2) ^ fK)) = vv;
        }
    };
    auto COMPUTE = [&](int bufb) {
#pragma unroll
        for (int kh = 0; kh < 2; ++kh) {
            const int u = kh * 4 + (l >> 4);
            bf16x8 af[2], bfr[2];
#pragma unroll
            for (int i = 0; i < 2; ++i) {
                const int row = wrA + i * 16 + (l & 15);
                af[i] = *(const bf16x8*)(Pl + bufb * 8192 +
                                         ((row * 128 + u * 16) ^ ((row & 7) << 4)));
            }
#pragma unroll
            for (int j = 0; j < 2; ++j) {
                const int kcol = wcB + j * 16 + (l & 15);
                const int fKc = ((kcol & 7) << 4) | (((kcol >> 3) & 1) << 3);
                const int addrA = kcol * 128 + kh * 64 + (l >> 4) * 16;
                u32x2 lo = *(const u32x2*)(Xl + bufb * 8192 + (addrA ^ fKc));
                u32x2 hi = *(const u32x2*)(Xl + bufb * 8192 + ((addrA + 8) ^ fKc));
                u32x4 uu = {lo[0], lo[1], hi[0], hi[1]};
                bfr[j] = __builtin_bit_cast(bf16x8, uu);
            }
#pragma unroll
            for (int i = 0; i < 2; ++i)
#pragma unroll
                for (int j = 0; j < 2; ++j)
                    acc[i][j] = __builtin_amdgcn_mfma_f32_16x16x32_bf16(
                        af[i], bfr[j], acc[i][j], 0, 0, 0);
        }
    };

    STAGE(0, 0);
    __syncthreads();
    int buf = 0;
    for (int step = 0; step < 16; ++step) {
        if (step + 1 < 16) STAGE(buf ^ 1, step + 1);
        COMPUTE(buf);
        __syncthreads();
        buf ^= 1;
    }

    // ---- epilogue: frag -> LDS [hs 64][k 64] f32 -> coalesced y store
#pragma unroll
    for (int i = 0; i < 2; ++i)
#pragma unroll
        for (int j = 0; j < 2; ++j) {
            const int kcol = wcB + j * 16 + (l & 15);
#pragma unroll
            for (int r = 0; r < 4; ++r) {
                const int hs2 = wrA + i * 16 + (l >> 4) * 4 + r;
                *(float*)(smem + ((hs2 * 256 + kcol * 4) ^ ((hs2 & 7) << 4))) = acc[i][j][r];
            }
        }
    __syncthreads();
    const int hs2 = t >> 2;
#pragma unroll
    for (int i = 0; i < 4; ++i) {
        const int seg = (t & 3) + i * 4;
        f32x4 v = *(const f32x4*)(smem + ((hs2 * 256 + seg * 16) ^ ((hs2 & 7) << 4)));
        *(f32x4*)&y[(size_t)(b * 64 + hs2) * 768 + k0 + seg * 4] = v;
    }
}

// ---------------------------------------------------------------------------
// K4: out[b][hs][d] = sum_k y[b,hs,k]*Wk[k,h*64+d] + bk[h*64+d]
// 256 blocks = (h 16) x (b-pair 16), 256 thr = 4 k-partitions x 64 d.
// ---------------------------------------------------------------------------
__global__ __launch_bounds__(256) void out_kernel(const float* __restrict__ y,
                                                  const float* __restrict__ wk,
                                                  const float* __restrict__ bk,
                                                  float* __restrict__ out) {
    __shared__ float ylds[8 * 768];  // 24 KB
    __shared__ float red[2048];      // 8 KB
    const int t = threadIdx.x;
    const int vid = (blockIdx.x & 7) * 32 + (blockIdx.x >> 3);  // same-h grouped per XCD
    const int h = vid >> 4, bp = vid & 15;
#pragma unroll
    for (int r = 0; r < 8; ++r) {
        const int gb = bp * 2 + (r >> 2);
        const int hs = h * 4 + (r & 3);
#pragma unroll
        for (int i = 0; i < 3; ++i)
            ylds[r * 768 + i * 256 + t] = y[(size_t)(gb * 64 + hs) * 768 + i * 256 + t];
    }
    __syncthreads();
    const int kp = t >> 6, d = t & 63;
    float acc[8] = {0.f, 0.f, 0.f, 0.f, 0.f, 0.f, 0.f, 0.f};
    for (int i = 0; i < 48; ++i) {
        const int k = kp * 192 + i * 4;
        const float wv0 = wk[(size_t)(k + 0) * 1024 + h * 64 + d];
        const float wv1 = wk[(size_t)(k + 1) * 1024 + h * 64 + d];
        const float wv2 = wk[(size_t)(k + 2) * 1024 + h * 64 + d];
        const float wv3 = wk[(size_t)(k + 3) * 1024 + h * 64 + d];
#pragma unroll
        for (int r = 0; r < 8; ++r) {
            f32x4 yv = *(const f32x4*)&ylds[r * 768 + k];
            acc[r] += yv[0] * wv0 + yv[1] * wv1 + yv[2] * wv2 + yv[3] * wv3;
        }
    }
#pragma unroll
    for (int r = 0; r < 8; ++r) red[(r * 64 + d) * 4 + kp] = acc[r];
    __syncthreads();
#pragma unroll
    for (int i = 0; i < 2; ++i) {
        const int o = i * 256 + t;
        const int r = o >> 6, dd = o & 63;
        f32x4 pv = *(const f32x4*)&red[o * 4];
        const float s = pv[0] + pv[1] + pv[2] + pv[3] + bk[h * 64 + dd];
        const int gb = bp * 2 + (r >> 2);
        out[(size_t)(gb * 64 + h * 4 + (r & 3)) * 64 + dd] = s;
    }
}

// ---------------------------------------------------------------------------
extern "C" void kernel_launch(void* const* d_in, const int* in_sizes, int n_in,
                              void* d_out, int out_size, void* d_ws, size_t ws_size,
                              hipStream_t stream) {
    const float* x     = (const float*)d_in[0];   // (32,1024,768)
    const int*   eos   = (const int*)d_in[1];     // (32,)
    const float* q_emb = (const float*)d_in[2];   // (16,4,64)
    const float* Wk    = (const float*)d_in[3];   // (768,1024)
    const float* bk    = (const float*)d_in[4];   // (1024,)
    float* out = (float*)d_out;

    char* ws = (char*)d_ws;
    __bf16* qwT      = (__bf16*)ws;                      // 96 KB  [hs 64][k 768] (swizzled)
    __bf16* Lg       = (__bf16*)(ws + 131072);           // 4 MB   [b][hs][n] bf16
    float*  partials = (float*)(ws + 4325376);           // 128 KB [b][chunk 8][hs][2]
    float*  y        = (float*)(ws + 4456448);           // 6 MB   [b][hs][k]

    qw_kernel<<<dim3(12, 16), 256, 0, stream>>>(q_emb, Wk, qwT);
    logits_kernel<<<dim3(256), 512, 0, stream>>>(x, qwT, eos, Lg, partials);
    pv_kernel<<<dim3(384), 256, 0, stream>>>(x, Lg, partials, y);
    out_kernel<<<dim3(256), 256, 0, stream>>>(y, Wk, bk, out);
}

// Round 12
// 63.604 us; speedup vs baseline: 1.1006x; 1.1006x over previous
//
#include <hip/hip_runtime.h>
#include <hip/hip_bf16.h>
#include <stdint.h>

typedef float  f32x4  __attribute__((ext_vector_type(4)));
typedef __bf16 bf16x4 __attribute__((ext_vector_type(4)));
typedef __bf16 bf16x8 __attribute__((ext_vector_type(8)));
typedef unsigned int u32x2 __attribute__((ext_vector_type(2)));
typedef unsigned int u32x4 __attribute__((ext_vector_type(4)));

#define AS1 __attribute__((address_space(1)))
#define AS3 __attribute__((address_space(3)))

__device__ __forceinline__ void async_load16(const void* g, void* lds) {
    __builtin_amdgcn_global_load_lds((const AS1 unsigned int*)g,
                                     (AS3 unsigned int*)lds, 16, 0, 0);
}

// ---------------------------------------------------------------------------
// K1: qw[hs][k] = scale * sum_d q[h,s,d] * Wk[k, h*64+d]  (bf16, [hs][768] linear)
// ---------------------------------------------------------------------------
__global__ __launch_bounds__(256) void qw_kernel(const float* __restrict__ q_emb,
                                                 const float* __restrict__ wk,
                                                 __bf16* __restrict__ qwT) {
    __shared__ float qlds[256];
    __shared__ float part[4096];  // [k 64][s 4][dseg 16]
    const int t = threadIdx.x;
    const int kc = blockIdx.x;   // 0..11
    const int h  = blockIdx.y;   // 0..15
    const int k0 = kc * 64;
    qlds[t] = q_emb[h * 256 + t] * 0.125f;   // scale = D^-0.5 = 1/8
    __syncthreads();
    const int dseg = t & 15;
    const int krow = t >> 4;   // 0..15
#pragma unroll
    for (int i = 0; i < 4; ++i) {
        const int k = i * 16 + krow;
        f32x4 wv = *(const f32x4*)&wk[(size_t)(k0 + k) * 1024 + h * 64 + dseg * 4];
#pragma unroll
        for (int s = 0; s < 4; ++s) {
            float p = qlds[s * 64 + dseg * 4 + 0] * wv[0]
                    + qlds[s * 64 + dseg * 4 + 1] * wv[1]
                    + qlds[s * 64 + dseg * 4 + 2] * wv[2]
                    + qlds[s * 64 + dseg * 4 + 3] * wv[3];
            part[k * 64 + s * 16 + dseg] = p;
        }
    }
    __syncthreads();
    const int k = t >> 2, s = t & 3;
    const float* pp = &part[k * 64 + s * 16];
    float sum = 0.f;
#pragma unroll
    for (int j = 0; j < 16; ++j) sum += pp[j];
    qwT[(h * 4 + s) * 768 + k0 + k] = (__bf16)sum;
}

// ---------------------------------------------------------------------------
// K2: fused chunk kernel. Block = (b, c): 64 n-rows.
//   Fully-masked chunks (c*64 > eos) write partials and EXIT (no compute).
//   Phase A: QK over K=768 (12 steps) -> l[64n][64hs]; stats m_c,s_c; P=e^{l-m_c}
//   Phase B: u_c[hs][k] = P @ x_chunk (12 kc slices, x re-read from L2/L3),
//            stored bf16 in raw MFMA-fragment layout.
// grid 512 = (b 32)x(c 16), XCD-swizzled; 256 threads (4 waves).
// ---------------------------------------------------------------------------
__global__ __launch_bounds__(256) void fused_chunk(const float* __restrict__ x,
                                                   const __bf16* __restrict__ qwT,
                                                   const int* __restrict__ eos_idx,
                                                   float* __restrict__ partials,
                                                   __bf16* __restrict__ u) {
    __shared__ char smem[32768];
    char* R0 = smem;          // 16KB: qw dbuf (A) / l-image / xT dbuf (B)
    char* R1 = smem + 16384;  // 16KB: x dbuf (A) / P_img (B)
    const int t = threadIdx.x, l = t & 63, w = t >> 6;   // 4 waves
    const int vid = ((blockIdx.x & 7) << 6) + (blockIdx.x >> 3);  // bijective XCD
    const int b = vid >> 4, c = vid & 15;
    const int eosb = eos_idx[b];
    float* pb = partials + ((size_t)(b * 16 + c) * 64) * 2;

    if (c * 64 > eosb) {          // fully masked -> no contribution
        if (t < 64) { pb[t * 2] = -INFINITY; pb[t * 2 + 1] = 0.f; }
        return;
    }

    const int wrA = (w >> 1) * 32;   // n-row group (phase A) / hs group (phase B)
    const int wcB = (w & 1) * 32;    // hs group (phase A) / k group (phase B)

    // ================== phase A: l[n][hs] = x_chunk @ qw^T ==================
    f32x4 acc[2][2];
#pragma unroll
    for (int i = 0; i < 2; ++i)
#pragma unroll
        for (int j = 0; j < 2; ++j) acc[i][j] = (f32x4)0.f;

    const int qcol = t >> 3, qseg = t & 7;
    const __bf16* qsrc0 = qwT + qcol * 768 + ((qseg ^ (qcol & 7)) * 8);
    const __bf16* qsrc1 = qsrc0 + 32 * 768;     // (qcol+32)&7 == qcol&7
    const int xr = t >> 2, xseg = (t & 3) * 16;
    const float* xrow = &x[(size_t)(b * 1024 + c * 64 + xr) * 768 + xseg];
    const int fR = (xr & 7) << 4;
    const int Adst0 = (xr * 128 + xseg * 2) ^ fR;
    const int Adst1 = (xr * 128 + xseg * 2 + 16) ^ fR;

    f32x4 xv0, xv1, xv2, xv3;
    // prologue (kt = 0)
    async_load16(qsrc0, R0 + t * 16);
    async_load16(qsrc1, R0 + 4096 + t * 16);
    xv0 = *(const f32x4*)(xrow);
    xv1 = *(const f32x4*)(xrow + 4);
    xv2 = *(const f32x4*)(xrow + 8);
    xv3 = *(const f32x4*)(xrow + 12);
    {
        bf16x8 v0 = {(__bf16)xv0[0], (__bf16)xv0[1], (__bf16)xv0[2], (__bf16)xv0[3],
                     (__bf16)xv1[0], (__bf16)xv1[1], (__bf16)xv1[2], (__bf16)xv1[3]};
        bf16x8 v1 = {(__bf16)xv2[0], (__bf16)xv2[1], (__bf16)xv2[2], (__bf16)xv2[3],
                     (__bf16)xv3[0], (__bf16)xv3[1], (__bf16)xv3[2], (__bf16)xv3[3]};
        *(bf16x8*)(R1 + Adst0) = v0;
        *(bf16x8*)(R1 + Adst1) = v1;
    }
    asm volatile("s_waitcnt vmcnt(0)" ::: "memory");
    __syncthreads();

    int buf = 0;
    for (int step = 0; step < 12; ++step) {
        const int nbuf = buf ^ 1;
        const bool more = (step + 1) < 12;
        if (more) {
            const int kt = (step + 1) * 64;
            async_load16(qsrc0 + kt, R0 + nbuf * 8192 + t * 16);
            async_load16(qsrc1 + kt, R0 + nbuf * 8192 + 4096 + t * 16);
            xv0 = *(const f32x4*)(xrow + kt);
            xv1 = *(const f32x4*)(xrow + kt + 4);
            xv2 = *(const f32x4*)(xrow + kt + 8);
            xv3 = *(const f32x4*)(xrow + kt + 12);
        }
#pragma unroll
        for (int kh = 0; kh < 2; ++kh) {
            const int koff = (kh * 32 + (l >> 4) * 8) * 2;
            bf16x8 af[2], bfr[2];
#pragma unroll
            for (int i = 0; i < 2; ++i) {
                const int row = wrA + i * 16 + (l & 15);
                af[i] = *(const bf16x8*)(R1 + buf * 8192 +
                                         ((row * 128 + koff) ^ ((row & 7) << 4)));
            }
#pragma unroll
            for (int j = 0; j < 2; ++j) {
                const int col = wcB + j * 16 + (l & 15);
                bfr[j] = *(const bf16x8*)(R0 + buf * 8192 +
                                          ((col * 128 + koff) ^ ((col & 7) << 4)));
            }
#pragma unroll
            for (int i = 0; i < 2; ++i)
#pragma unroll
                for (int j = 0; j < 2; ++j)
                    acc[i][j] = __builtin_amdgcn_mfma_f32_16x16x32_bf16(
                        af[i], bfr[j], acc[i][j], 0, 0, 0);
        }
        if (more) {
            bf16x8 v0 = {(__bf16)xv0[0], (__bf16)xv0[1], (__bf16)xv0[2], (__bf16)xv0[3],
                         (__bf16)xv1[0], (__bf16)xv1[1], (__bf16)xv1[2], (__bf16)xv1[3]};
            bf16x8 v1 = {(__bf16)xv2[0], (__bf16)xv2[1], (__bf16)xv2[2], (__bf16)xv2[3],
                         (__bf16)xv3[0], (__bf16)xv3[1], (__bf16)xv3[2], (__bf16)xv3[3]};
            *(bf16x8*)(R1 + nbuf * 8192 + Adst0) = v0;
            *(bf16x8*)(R1 + nbuf * 8192 + Adst1) = v1;
        }
        asm volatile("s_waitcnt vmcnt(0)" ::: "memory");
        __syncthreads();
        buf = nbuf;
    }

    // ---- l-image [hs 64][n 64] f32 in R0 (16KB)
#pragma unroll
    for (int i = 0; i < 2; ++i)
#pragma unroll
        for (int j = 0; j < 2; ++j) {
            const int hs = wcB + j * 16 + (l & 15);
            const int n4 = wrA + i * 16 + (l >> 4) * 4;
            *(f32x4*)(R0 + ((hs * 256 + n4 * 4) ^ ((hs & 7) << 4))) = acc[i][j];
        }
    __syncthreads();

    // ---- stats (m_c, s_c) + P = e^{l - m_c} (unnormalized) into R1
    {
        const int hs = t >> 2, sg = t & 3;
        const int fH = (hs & 7) << 4;
        f32x4 v[4];
        float mx = -INFINITY;
#pragma unroll
        for (int q = 0; q < 4; ++q) {
            const int n = sg * 16 + q * 4;
            f32x4 vv = *(const f32x4*)(R0 + ((hs * 256 + n * 4) ^ fH));
#pragma unroll
            for (int e = 0; e < 4; ++e) {
                if (c * 64 + n + e > eosb) vv[e] = -INFINITY;
                mx = fmaxf(mx, vv[e]);
            }
            v[q] = vv;
        }
#pragma unroll
        for (int off = 1; off < 4; off <<= 1) mx = fmaxf(mx, __shfl_xor(mx, off));
        // chunk is non-skipped => at least n = c*64 valid => mx finite
        float sl = 0.f;
#pragma unroll
        for (int q = 0; q < 4; ++q)
#pragma unroll
            for (int e = 0; e < 4; ++e) sl += __expf(v[q][e] - mx);  // exp(-inf)=0
#pragma unroll
        for (int off = 1; off < 4; off <<= 1) sl += __shfl_xor(sl, off);
        if (sg == 0) { pb[hs * 2] = mx; pb[hs * 2 + 1] = sl; }
        bf16x8 p0, p1;
#pragma unroll
        for (int e = 0; e < 4; ++e) {
            p0[e]     = (__bf16)__expf(v[0][e] - mx);
            p0[4 + e] = (__bf16)__expf(v[1][e] - mx);
            p1[e]     = (__bf16)__expf(v[2][e] - mx);
            p1[4 + e] = (__bf16)__expf(v[3][e] - mx);
        }
        *(bf16x8*)(R1 + ((hs * 128 + sg * 32) ^ fH)) = p0;
        *(bf16x8*)(R1 + ((hs * 128 + sg * 32 + 16) ^ fH)) = p1;
    }
    __syncthreads();

    // ================== phase B: u_c[hs][k] = P @ x_chunk ==================
    const float* xcb = x + (size_t)(b * 1024 + c * 64) * 768 + l;  // k-col base
    const int fK = ((l & 7) << 4) | (((l >> 3) & 1) << 3);

    auto STAGE = [&](int bufb, int kc) {
        float xv[16];
#pragma unroll
        for (int i_ = 0; i_ < 4; ++i_)
#pragma unroll
            for (int j_ = 0; j_ < 4; ++j_)
                xv[i_ * 4 + j_] = xcb[(size_t)(i_ * 16 + w * 4 + j_) * 768 + kc * 64];
#pragma unroll
        for (int i_ = 0; i_ < 4; ++i_) {
            bf16x4 vv = {(__bf16)xv[i_ * 4 + 0], (__bf16)xv[i_ * 4 + 1],
                         (__bf16)xv[i_ * 4 + 2], (__bf16)xv[i_ * 4 + 3]};
            *(bf16x4*)(R0 + bufb * 8192 + ((l * 128 + (i_ * 16 + w * 4) * 2) ^ fK)) = vv;
        }
    };

    f32x4 acc2[2][2];
    STAGE(0, 0);
    __syncthreads();
    int bufb = 0;
    for (int kc = 0; kc < 12; ++kc) {
        if (kc + 1 < 12) STAGE(bufb ^ 1, kc + 1);
#pragma unroll
        for (int i = 0; i < 2; ++i)
#pragma unroll
            for (int j = 0; j < 2; ++j) acc2[i][j] = (f32x4)0.f;
#pragma unroll
        for (int kh = 0; kh < 2; ++kh) {
            const int u8 = kh * 4 + (l >> 4);
            bf16x8 af[2], bfr[2];
#pragma unroll
            for (int i = 0; i < 2; ++i) {
                const int row = wrA + i * 16 + (l & 15);
                af[i] = *(const bf16x8*)(R1 + ((row * 128 + u8 * 16) ^ ((row & 7) << 4)));
            }
#pragma unroll
            for (int j = 0; j < 2; ++j) {
                const int kcol = wcB + j * 16 + (l & 15);
                const int fKc = ((kcol & 7) << 4) | (((kcol >> 3) & 1) << 3);
                const int addrA = kcol * 128 + kh * 64 + (l >> 4) * 16;
                u32x2 lo = *(const u32x2*)(R0 + bufb * 8192 + (addrA ^ fKc));
                u32x2 hi = *(const u32x2*)(R0 + bufb * 8192 + ((addrA + 8) ^ fKc));
                u32x4 uu = {lo[0], lo[1], hi[0], hi[1]};
                bfr[j] = __builtin_bit_cast(bf16x8, uu);
            }
#pragma unroll
            for (int i = 0; i < 2; ++i)
#pragma unroll
                for (int j = 0; j < 2; ++j)
                    acc2[i][j] = __builtin_amdgcn_mfma_f32_16x16x32_bf16(
                        af[i], bfr[j], acc2[i][j], 0, 0, 0);
        }
        // u store in raw fragment layout: [(bc,kc)][w][fr][lane][4] bf16
        {
            const size_t fb = (((size_t)(b * 16 + c) * 12 + kc) * 4 + w) * 4;
#pragma unroll
            for (int i = 0; i < 2; ++i)
#pragma unroll
                for (int j = 0; j < 2; ++j) {
                    bf16x4 uv = {(__bf16)acc2[i][j][0], (__bf16)acc2[i][j][1],
                                 (__bf16)acc2[i][j][2], (__bf16)acc2[i][j][3]};
                    *(bf16x4*)&u[(fb + i * 2 + j) * 256 + l * 4] = uv;
                }
        }
        __syncthreads();
        bufb ^= 1;
    }
}

// ---------------------------------------------------------------------------
// K3: combine. Per (b,kc): weights e^{m_c-M}/S, y = sum_c wgt_c * u_c.
// grid 384 = 32 b x 12 kc (XCD-swizzled), 256 thr.
// ---------------------------------------------------------------------------
__global__ __launch_bounds__(256) void combine_kernel(const float* __restrict__ partials,
                                                      const __bf16* __restrict__ u,
                                                      const int* __restrict__ eos_idx,
                                                      float* __restrict__ y) {
    __shared__ char smem[16384];      // y transpose
    __shared__ float wgt[16 * 64];    // [c][hs]
    const int t = threadIdx.x, l = t & 63, w = t >> 6;
    const int vid = (blockIdx.x & 7) * 48 + (blockIdx.x >> 3);
    const int b = vid / 12, kc = vid % 12;
    const int nact = (eos_idx[b] >> 6) + 1;   // active chunks

    if (t < 64) {
        const float* pbb = partials + (size_t)b * 2048;  // [c 16][hs 64][2]
        float M = -INFINITY;
        for (int c = 0; c < nact; ++c) M = fmaxf(M, pbb[(c * 64 + t) * 2]);
        float S = 0.f;
        for (int c = 0; c < nact; ++c) {
            float2 p = *(const float2*)&pbb[(c * 64 + t) * 2];
            S += __expf(p.x - M) * p.y;
        }
        const float inv = 1.0f / S;
        for (int c = 0; c < nact; ++c)
            wgt[c * 64 + t] = __expf(pbb[(c * 64 + t) * 2] - M) * inv;
    }
    __syncthreads();

    const int wrA = (w >> 1) * 32, wcB = (w & 1) * 32;
    f32x4 yf[2][2];
#pragma unroll
    for (int i = 0; i < 2; ++i)
#pragma unroll
        for (int j = 0; j < 2; ++j) yf[i][j] = (f32x4)0.f;

    for (int c = 0; c < nact; ++c) {
        const size_t fb = (((size_t)(b * 16 + c) * 12 + kc) * 4 + w) * 4;
        f32x4 wv[2];
#pragma unroll
        for (int i = 0; i < 2; ++i)
            wv[i] = *(const f32x4*)&wgt[c * 64 + wrA + i * 16 + (l >> 4) * 4];
#pragma unroll
        for (int i = 0; i < 2; ++i)
#pragma unroll
            for (int j = 0; j < 2; ++j) {
                bf16x4 uv = *(const bf16x4*)&u[(fb + i * 2 + j) * 256 + l * 4];
#pragma unroll
                for (int r = 0; r < 4; ++r)
                    yf[i][j][r] += wv[i][r] * (float)uv[r];
            }
    }

    // transpose via LDS -> coalesced y write
#pragma unroll
    for (int i = 0; i < 2; ++i)
#pragma unroll
        for (int j = 0; j < 2; ++j) {
            const int kcol = wcB + j * 16 + (l & 15);
#pragma unroll
            for (int r = 0; r < 4; ++r) {
                const int hs2 = wrA + i * 16 + (l >> 4) * 4 + r;
                *(float*)(smem + ((hs2 * 256 + kcol * 4) ^ ((hs2 & 7) << 4))) = yf[i][j][r];
            }
        }
    __syncthreads();
    const int hs2 = t >> 2;
#pragma unroll
    for (int i = 0; i < 4; ++i) {
        const int seg = (t & 3) + i * 4;
        f32x4 v = *(const f32x4*)(smem + ((hs2 * 256 + seg * 16) ^ ((hs2 & 7) << 4)));
        *(f32x4*)&y[(size_t)(b * 64 + hs2) * 768 + kc * 64 + seg * 4] = v;
    }
}

// ---------------------------------------------------------------------------
// K4: out[b][hs][d] = sum_k y[b,hs,k]*Wk[k,h*64+d] + bk[h*64+d]
// ---------------------------------------------------------------------------
__global__ __launch_bounds__(256) void out_kernel(const float* __restrict__ y,
                                                  const float* __restrict__ wk,
                                                  const float* __restrict__ bk,
                                                  float* __restrict__ out) {
    __shared__ float ylds[8 * 768];  // 24 KB
    __shared__ float red[2048];      // 8 KB
    const int t = threadIdx.x;
    const int vid = (blockIdx.x & 7) * 32 + (blockIdx.x >> 3);
    const int h = vid >> 4, bp = vid & 15;
#pragma unroll
    for (int r = 0; r < 8; ++r) {
        const int gb = bp * 2 + (r >> 2);
        const int hs = h * 4 + (r & 3);
#pragma unroll
        for (int i = 0; i < 3; ++i)
            ylds[r * 768 + i * 256 + t] = y[(size_t)(gb * 64 + hs) * 768 + i * 256 + t];
    }
    __syncthreads();
    const int kp = t >> 6, d = t & 63;
    float acc[8] = {0.f, 0.f, 0.f, 0.f, 0.f, 0.f, 0.f, 0.f};
    for (int i = 0; i < 48; ++i) {
        const int k = kp * 192 + i * 4;
        const float wv0 = wk[(size_t)(k + 0) * 1024 + h * 64 + d];
        const float wv1 = wk[(size_t)(k + 1) * 1024 + h * 64 + d];
        const float wv2 = wk[(size_t)(k + 2) * 1024 + h * 64 + d];
        const float wv3 = wk[(size_t)(k + 3) * 1024 + h * 64 + d];
#pragma unroll
        for (int r = 0; r < 8; ++r) {
            f32x4 yv = *(const f32x4*)&ylds[r * 768 + k];
            acc[r] += yv[0] * wv0 + yv[1] * wv1 + yv[2] * wv2 + yv[3] * wv3;
        }
    }
#pragma unroll
    for (int r = 0; r < 8; ++r) red[(r * 64 + d) * 4 + kp] = acc[r];
    __syncthreads();
#pragma unroll
    for (int i = 0; i < 2; ++i) {
        const int o = i * 256 + t;
        const int r = o >> 6, dd = o & 63;
        f32x4 pv = *(const f32x4*)&red[o * 4];
        const float s = pv[0] + pv[1] + pv[2] + pv[3] + bk[h * 64 + dd];
        const int gb = bp * 2 + (r >> 2);
        out[(size_t)(gb * 64 + h * 4 + (r & 3)) * 64 + dd] = s;
    }
}

// ---------------------------------------------------------------------------
extern "C" void kernel_launch(void* const* d_in, const int* in_sizes, int n_in,
                              void* d_out, int out_size, void* d_ws, size_t ws_size,
                              hipStream_t stream) {
    const float* x     = (const float*)d_in[0];   // (32,1024,768)
    const int*   eos   = (const int*)d_in[1];     // (32,)
    const float* q_emb = (const float*)d_in[2];   // (16,4,64)
    const float* Wk    = (const float*)d_in[3];   // (768,1024)
    const float* bk    = (const float*)d_in[4];   // (1024,)
    float* out = (float*)d_out;

    char* ws = (char*)d_ws;
    __bf16* qwT      = (__bf16*)ws;                       // 96 KB  [hs][k] linear
    float*  partials = (float*)(ws + 131072);             // 256 KB [b][c 16][hs][2]
    __bf16* u        = (__bf16*)(ws + 393216);            // 48 MB  frag layout
    float*  y        = (float*)(ws + 393216 + 50331648);  // 6 MB   [b][hs][k]

    qw_kernel<<<dim3(12, 16), 256, 0, stream>>>(q_emb, Wk, qwT);
    fused_chunk<<<dim3(512), 256, 0, stream>>>(x, qwT, eos, partials, u);
    combine_kernel<<<dim3(384), 256, 0, stream>>>(partials, u, eos, y);
    out_kernel<<<dim3(256), 256, 0, stream>>>(y, Wk, bk, out);
}